// Round 1
// baseline (610.506 us; speedup 1.0000x reference)
//
#include <hip/hip_runtime.h>

typedef _Float16 f16;
typedef f16 f16x8 __attribute__((ext_vector_type(8)));
typedef f16 f16x4 __attribute__((ext_vector_type(4)));
typedef f16 f16x2 __attribute__((ext_vector_type(2)));
typedef float f32x4 __attribute__((ext_vector_type(4)));

#define MFMA16(a,b,c) __builtin_amdgcn_mfma_f32_16x16x32_f16((a),(b),(c),0,0,0)

static __device__ __forceinline__ f16x8 ld8(const f16* p){ return *(const f16x8*)p; }
static __device__ __forceinline__ float sigm(float x){ return 1.f/(1.f + __expf(-x)); }

// ---------------------------------------------------------------------------
// Weight prep: fold gammas, cast fp16, store transposed (N rows x K cols) so
// B-fragments are contiguous 16B along K. Wa1/Wa2 interleaved by column pairs.
// ---------------------------------------------------------------------------
__global__ __launch_bounds__(256) void k_prep(
    const float* __restrict__ apb_gamma, const float* __restrict__ apb_Wg, const float* __restrict__ apb_Wskip,
    const float* __restrict__ ct_gamma,  const float* __restrict__ ct_Wg,  const float* __restrict__ ct_Wskip,
    const float* __restrict__ Wq, const float* __restrict__ Wk, const float* __restrict__ Wv, const float* __restrict__ Wgate,
    const float* __restrict__ Wsl, const float* __restrict__ Wss,
    const float* __restrict__ Wa1, const float* __restrict__ Wa2,
    const float* __restrict__ Wo, const float* __restrict__ Wb,
    const float* __restrict__ gamma_z, const float* __restrict__ Wz,
    f16* __restrict__ wA, f16* __restrict__ wC, f16* __restrict__ wQK, f16* __restrict__ wVG,
    f16* __restrict__ wSG, f16* __restrict__ wAB, f16* __restrict__ wO, f16* __restrict__ wBt,
    float* __restrict__ wzg)
{
  const int t0 = blockIdx.x*256 + threadIdx.x;
  const int stride = gridDim.x*256;
  for (int i = t0; i < 256*128; i += stride){
    const int n = i >> 7, k = i & 127;
    const int m = n & 127;
    wA[i]  = (f16)(((n<128) ? apb_Wg[k*128+m] : apb_Wskip[k*128+m]) * apb_gamma[k]);
    wC[i]  = (f16)(((n<128) ? ct_Wg[k*128+m]  : ct_Wskip[k*128+m])  * ct_gamma[k]);
    wQK[i] = (f16)((n<128) ? Wq[k*128+m] : Wk[k*128+m]);
    wVG[i] = (f16)((n<128) ? Wv[k*128+m] : Wgate[k*128+m]);
    wSG[i] = (f16)((n<128) ? Wsl[k*128+m] : Wss[k*128+m]);
  }
  for (int i = t0; i < 512*128; i += stride){
    const int n = i >> 7, k = i & 127;
    wAB[i] = (f16)((n & 1) ? Wa2[k*256 + (n>>1)] : Wa1[k*256 + (n>>1)]);
  }
  for (int i = t0; i < 128*128; i += stride){
    const int n = i >> 7, k = i & 127;
    wO[i] = (f16)Wo[k*128+n];
  }
  for (int i = t0; i < 128*256; i += stride){
    const int n = i >> 8, k = i & 255;
    wBt[i] = (f16)Wb[k*128+n];
  }
  if (t0 < 64) wzg[t0] = gamma_z[t0 & 15] * Wz[(t0 & 15)*4 + (t0 >> 4)];
}

// ---------------------------------------------------------------------------
// LayerNorm of a and s (fp32 stats), plus fp16 copy of raw s.
// One wave per row pair (a-row and s-row with same index).
// ---------------------------------------------------------------------------
__global__ __launch_bounds__(256) void k_ln(const float* __restrict__ A, const float* __restrict__ S,
    f16* __restrict__ An, f16* __restrict__ Sn, f16* __restrict__ Sh)
{
  const int w = threadIdx.x >> 6, l = threadIdx.x & 63;
  const size_t row = (size_t)blockIdx.x*4 + w;
  const float2 av = *(const float2*)(A + row*128 + l*2);
  const float2 sv = *(const float2*)(S + row*128 + l*2);
  float sa = av.x + av.y, qa = av.x*av.x + av.y*av.y;
  float ss = sv.x + sv.y, qs = sv.x*sv.x + sv.y*sv.y;
  #pragma unroll
  for (int o = 32; o; o >>= 1){
    sa += __shfl_xor(sa, o); qa += __shfl_xor(qa, o);
    ss += __shfl_xor(ss, o); qs += __shfl_xor(qs, o);
  }
  const float ma = sa*(1.f/128.f), va = qa*(1.f/128.f) - ma*ma;
  const float ms = ss*(1.f/128.f), vs = qs*(1.f/128.f) - ms*ms;
  const float ra = rsqrtf(va + 1e-5f), rs = rsqrtf(vs + 1e-5f);
  f16x2 o1; o1[0] = (f16)((av.x-ma)*ra); o1[1] = (f16)((av.y-ma)*ra);
  *(f16x2*)(An + row*128 + l*2) = o1;
  f16x2 o2; o2[0] = (f16)((sv.x-ms)*rs); o2[1] = (f16)((sv.y-ms)*rs);
  *(f16x2*)(Sn + row*128 + l*2) = o2;
  f16x2 o3; o3[0] = (f16)sv.x; o3[1] = (f16)sv.y;
  *(f16x2*)(Sh + row*128 + l*2) = o3;
}

// ---------------------------------------------------------------------------
// Skinny GEMM: X (32768 x 128 f16) @ Wt^T (Wt is 256 x 128 f16, N-major).
// Each wave: 16 rows x two 16-col tiles (cols n0+c and 128+n0+c), K=128.
// B-fragments held in registers across a 4-iteration M loop.
// MODE 0: adaLN   out0 = sigmoid(d0+bias0)*a_n + d1
// MODE 1: gates   out0 = sigmoid(d0+bias0), out1 = sigmoid(d1+bias1)
// MODE 2: q/k     out0 = (d0+bias0)/sqrt(32), out1 = d1
// MODE 3: v/gate  out0 = v transposed [b][c][n], out1 = sigmoid(d1)
// ---------------------------------------------------------------------------
template<int MODE>
__global__ __launch_bounds__(256) void k_gemm256(
    const f16* __restrict__ X, const f16* __restrict__ Wt,
    const float* __restrict__ bias0, const float* __restrict__ bias1,
    const f16* __restrict__ aux, f16* __restrict__ out0, f16* __restrict__ out1)
{
  const int l = threadIdx.x & 63, w = threadIdx.x >> 6;
  const int c = l & 15, q4 = l >> 4;
  const int n0 = blockIdx.y * 16;
  f16x8 b0[4], b1[4];
  #pragma unroll
  for (int kc = 0; kc < 4; kc++){
    b0[kc] = ld8(Wt + (size_t)(n0 + c)*128 + kc*32 + q4*8);
    b1[kc] = ld8(Wt + (size_t)(128 + n0 + c)*128 + kc*32 + q4*8);
  }
  float bv0 = 0.f, bv1 = 0.f;
  if (MODE == 0 || MODE == 1 || MODE == 2) bv0 = bias0[n0 + c];
  if (MODE == 1) bv1 = bias1[n0 + c];

  for (int mi = 0; mi < 4; mi++){
    const int mbase = blockIdx.x*256 + w*64 + mi*16;
    const f16* xp = X + (size_t)(mbase + c)*128 + q4*8;
    f32x4 d0 = {0.f,0.f,0.f,0.f}, d1 = {0.f,0.f,0.f,0.f};
    #pragma unroll
    for (int kc = 0; kc < 4; kc++){
      f16x8 av = ld8(xp + kc*32);
      d0 = MFMA16(av, b0[kc], d0);
      d1 = MFMA16(av, b1[kc], d1);
    }
    if (MODE == 0){
      #pragma unroll
      for (int r = 0; r < 4; r++){
        const size_t row = mbase + q4*4 + r;
        const float anv = (float)aux[row*128 + n0 + c];
        out0[row*128 + n0 + c] = (f16)(sigm(d0[r] + bv0)*anv + d1[r]);
      }
    } else if (MODE == 1){
      #pragma unroll
      for (int r = 0; r < 4; r++){
        const size_t row = mbase + q4*4 + r;
        out0[row*128 + n0 + c] = (f16)sigm(d0[r] + bv0);
        out1[row*128 + n0 + c] = (f16)sigm(d1[r] + bv1);
      }
    } else if (MODE == 2){
      #pragma unroll
      for (int r = 0; r < 4; r++){
        const size_t row = mbase + q4*4 + r;
        out0[row*128 + n0 + c] = (f16)((d0[r] + bv0)*0.17677669529663687f);
        out1[row*128 + n0 + c] = (f16)d1[r];
      }
    } else {
      // v transposed store: v_t[b][c][n], pack 4 consecutive tokens (8B)
      f16x4 vv;
      #pragma unroll
      for (int r = 0; r < 4; r++) vv[r] = (f16)d0[r];
      const int bidx = mbase >> 14;
      const int ntk  = (mbase & 16383) + q4*4;
      *(f16x4*)(out0 + ((size_t)bidx*128 + n0 + c)*16384 + ntk) = vv;
      #pragma unroll
      for (int r = 0; r < 4; r++){
        const size_t row = mbase + q4*4 + r;
        out1[row*128 + n0 + c] = (f16)sigm(d1[r]);
      }
    }
  }
}

// ---------------------------------------------------------------------------
// Transition: t = silu(a3@Wa1) * (a3@Wa2), Wa1/Wa2 column-interleaved in wAB
// (512 cols, N-major, K=128). silu pairing via shfl_xor(1).
// ---------------------------------------------------------------------------
__global__ __launch_bounds__(256) void k_ab(const f16* __restrict__ X, const f16* __restrict__ Wt,
                                            f16* __restrict__ T)
{
  const int l = threadIdx.x & 63, w = threadIdx.x >> 6;
  const int c = l & 15, q4 = l >> 4;
  const int n0 = blockIdx.y * 32;
  f16x8 b0[4], b1[4];
  #pragma unroll
  for (int kc = 0; kc < 4; kc++){
    b0[kc] = ld8(Wt + (size_t)(n0 + c)*128 + kc*32 + q4*8);
    b1[kc] = ld8(Wt + (size_t)(n0 + 16 + c)*128 + kc*32 + q4*8);
  }
  for (int mi = 0; mi < 4; mi++){
    const int mbase = blockIdx.x*256 + w*64 + mi*16;
    const f16* xp = X + (size_t)(mbase + c)*128 + q4*8;
    f32x4 d0 = {0.f,0.f,0.f,0.f}, d1 = {0.f,0.f,0.f,0.f};
    #pragma unroll
    for (int kc = 0; kc < 4; kc++){
      f16x8 av = ld8(xp + kc*32);
      d0 = MFMA16(av, b0[kc], d0);
      d1 = MFMA16(av, b1[kc], d1);
    }
    #pragma unroll
    for (int tile = 0; tile < 2; tile++){
      #pragma unroll
      for (int r = 0; r < 4; r++){
        const float dv = tile ? d1[r] : d0[r];
        const float ov = __shfl_xor(dv, 1);
        const float u  = (c & 1) ? ov : dv;
        const float vv = (c & 1) ? dv : ov;
        const float tvv = (u * sigm(u)) * vv;
        if (!(c & 1)){
          const size_t row = mbase + q4*4 + r;
          T[row*256 + ((n0 + tile*16 + c) >> 1)] = (f16)tvv;
        }
      }
    }
  }
}

// ---------------------------------------------------------------------------
// Fused windowed attention with in-kernel z-bias. One block per (b, nb).
// 8 waves: wave = (head h, query-half qh). z read exactly once from HBM.
// ---------------------------------------------------------------------------
__global__ __launch_bounds__(512) void k_attn(const f16* __restrict__ Q, const f16* __restrict__ K,
    const f16* __restrict__ VT, const float* __restrict__ Z, const float* __restrict__ WZG,
    f16* __restrict__ Og)
{
  __shared__ f16 kl[128*136];       // [key][c], c = h*32+d
  __shared__ f16 vtl[128*136];      // [c][key]
  __shared__ f16 upb[17408];        // phase1: bias[4][32][132]; phase2: p[8][16][136]
  __shared__ float wzg_s[64];
  const int tid = threadIdx.x;
  const int b = blockIdx.x >> 9, nb = blockIdx.x & 511;
  if (tid < 64) wzg_s[tid] = WZG[tid];
  {
    const int j = tid >> 2, seg = tid & 3;
    const long kt = (long)nb*32 - 48 + j;
    const f16* ks = K + ((long)b*16384 + kt)*128 + seg*32;       // OOB stays inside ws: finite garbage, masked later
    *(f16x8*)&kl[j*136 + seg*32]      = ld8(ks);
    *(f16x8*)&kl[j*136 + seg*32 + 8]  = ld8(ks + 8);
    *(f16x8*)&kl[j*136 + seg*32 + 16] = ld8(ks + 16);
    *(f16x8*)&kl[j*136 + seg*32 + 24] = ld8(ks + 24);
    const f16* vs = VT + ((long)b*128 + j)*16384 + (long)nb*32 - 48 + seg*32;
    *(f16x8*)&vtl[j*136 + seg*32]      = ld8(vs);
    *(f16x8*)&vtl[j*136 + seg*32 + 8]  = ld8(vs + 8);
    *(f16x8*)&vtl[j*136 + seg*32 + 16] = ld8(vs + 16);
    *(f16x8*)&vtl[j*136 + seg*32 + 24] = ld8(vs + 24);
  }
  __syncthreads();
  // z -> LN -> @ (gamma_z . Wz) -> bias tile in LDS (fp16)
  #pragma unroll
  for (int i = 0; i < 8; i++){
    const int p  = tid + i*512;
    const int qq = p >> 7, kk = p & 127;
    const float* zp = Z + ((((size_t)b*512 + nb)*32 + qq)*128 + kk)*16;
    const float4 z0 = *(const float4*)(zp);
    const float4 z1 = *(const float4*)(zp + 4);
    const float4 z2 = *(const float4*)(zp + 8);
    const float4 z3 = *(const float4*)(zp + 12);
    const float xs[16] = {z0.x,z0.y,z0.z,z0.w, z1.x,z1.y,z1.z,z1.w,
                          z2.x,z2.y,z2.z,z2.w, z3.x,z3.y,z3.z,z3.w};
    float sm = 0.f, sq = 0.f;
    #pragma unroll
    for (int cc = 0; cc < 16; cc++){ sm += xs[cc]; sq += xs[cc]*xs[cc]; }
    const float mean = sm*(1.f/16.f);
    const float var  = sq*(1.f/16.f) - mean*mean;
    const float rs   = rsqrtf(var + 1e-5f);
    #pragma unroll
    for (int h = 0; h < 4; h++){
      float acc = 0.f;
      #pragma unroll
      for (int cc = 0; cc < 16; cc++) acc += (xs[cc]-mean)*wzg_s[h*16+cc];
      upb[(h*32 + qq)*132 + kk] = (f16)(acc*rs);
    }
  }
  __syncthreads();

  const int l = tid & 63, w = tid >> 6;
  const int c = l & 15, q4 = l >> 4;
  const int h = w >> 1, qh = w & 1, m0 = qh*16;
  const f16x8 aq = ld8(Q + ((size_t)b*16384 + (size_t)nb*32 + m0 + c)*128 + h*32 + q4*8);
  f32x4 sc[8];
  #pragma unroll
  for (int nt = 0; nt < 8; nt++){
    const f16x8 bf = *(const f16x8*)&kl[(nt*16 + c)*136 + h*32 + q4*8];
    f32x4 zz = {0.f,0.f,0.f,0.f};
    sc[nt] = MFMA16(aq, bf, zz);
  }
  #pragma unroll
  for (int nt = 0; nt < 8; nt++){
    const int key = nt*16 + c;
    const long kt = (long)nb*32 - 48 + key;
    const bool inv = (kt < 0) || (kt >= 16384);
    #pragma unroll
    for (int r = 0; r < 4; r++){
      const float v = sc[nt][r] + (float)upb[(h*32 + m0 + q4*4 + r)*132 + key];
      sc[nt][r] = inv ? -1e9f : v;
    }
  }
  // softmax over 128 keys per row (row lives in the 16 lanes sharing q4)
  #pragma unroll
  for (int r = 0; r < 4; r++){
    float mx = sc[0][r];
    #pragma unroll
    for (int nt = 1; nt < 8; nt++) mx = fmaxf(mx, sc[nt][r]);
    #pragma unroll
    for (int o = 8; o; o >>= 1) mx = fmaxf(mx, __shfl_xor(mx, o));
    float sum = 0.f;
    #pragma unroll
    for (int nt = 0; nt < 8; nt++){ const float e = __expf(sc[nt][r]-mx); sc[nt][r] = e; sum += e; }
    #pragma unroll
    for (int o = 8; o; o >>= 1) sum += __shfl_xor(sum, o);
    const float inv = 1.f/sum;
    #pragma unroll
    for (int nt = 0; nt < 8; nt++) sc[nt][r] *= inv;
  }
  __syncthreads();   // all bias reads done -> reuse upb as P
  #pragma unroll
  for (int nt = 0; nt < 8; nt++)
    #pragma unroll
    for (int r = 0; r < 4; r++)
      upb[(w*16 + q4*4 + r)*136 + nt*16 + c] = (f16)sc[nt][r];
  // O = P @ V
  f32x4 o0 = {0.f,0.f,0.f,0.f}, o1 = {0.f,0.f,0.f,0.f};
  #pragma unroll
  for (int kc = 0; kc < 4; kc++){
    const f16x8 pa = *(const f16x8*)&upb[(w*16 + c)*136 + kc*32 + q4*8];
    const f16x8 v0 = *(const f16x8*)&vtl[(h*32 + c)*136 + kc*32 + q4*8];
    const f16x8 v1 = *(const f16x8*)&vtl[(h*32 + 16 + c)*136 + kc*32 + q4*8];
    o0 = MFMA16(pa, v0, o0);
    o1 = MFMA16(pa, v1, o1);
  }
  #pragma unroll
  for (int r = 0; r < 4; r++){
    const size_t tok = (size_t)b*16384 + (size_t)nb*32 + m0 + q4*4 + r;
    Og[tok*128 + h*32 + c]      = (f16)o0[r];
    Og[tok*128 + h*32 + 16 + c] = (f16)o1[r];
  }
}

// ---------------------------------------------------------------------------
// Final: out = gl * ((g.o) @ Wo) + gs * (t @ Wb).  Wo: K=128, Wb: K=256.
// ---------------------------------------------------------------------------
__global__ __launch_bounds__(256) void k_final(const f16* __restrict__ G, const f16* __restrict__ O,
    const f16* __restrict__ T, const f16* __restrict__ Wot, const f16* __restrict__ Wbt,
    const f16* __restrict__ GL, const f16* __restrict__ GS, float* __restrict__ out)
{
  const int l = threadIdx.x & 63, w = threadIdx.x >> 6;
  const int c = l & 15, q4 = l >> 4;
  #pragma unroll
  for (int nt = 0; nt < 2; nt++){
    const int cb = blockIdx.y*32 + nt*16;
    f16x8 bo[4], bb[8];
    #pragma unroll
    for (int kc = 0; kc < 4; kc++) bo[kc] = ld8(Wot + (size_t)(cb + c)*128 + kc*32 + q4*8);
    #pragma unroll
    for (int kc = 0; kc < 8; kc++) bb[kc] = ld8(Wbt + (size_t)(cb + c)*256 + kc*32 + q4*8);
    for (int mi = 0; mi < 4; mi++){
      const int mbase = blockIdx.x*256 + w*64 + mi*16;
      f32x4 d1 = {0.f,0.f,0.f,0.f}, d2 = {0.f,0.f,0.f,0.f};
      const f16* gp = G + (size_t)(mbase + c)*128 + q4*8;
      const f16* op = O + (size_t)(mbase + c)*128 + q4*8;
      #pragma unroll
      for (int kc = 0; kc < 4; kc++){
        const f16x8 av = ld8(gp + kc*32) * ld8(op + kc*32);
        d1 = MFMA16(av, bo[kc], d1);
      }
      const f16* tp = T + (size_t)(mbase + c)*256 + q4*8;
      #pragma unroll
      for (int kc = 0; kc < 8; kc++) d2 = MFMA16(ld8(tp + kc*32), bb[kc], d2);
      #pragma unroll
      for (int r = 0; r < 4; r++){
        const size_t row = mbase + q4*4 + r;
        const float glv = (float)GL[row*128 + cb + c];
        const float gsv = (float)GS[row*128 + cb + c];
        out[row*128 + cb + c] = glv*d1[r] + gsv*d2[r];
      }
    }
  }
}

// ---------------------------------------------------------------------------
extern "C" void kernel_launch(void* const* d_in, const int* in_sizes, int n_in,
                              void* d_out, int out_size, void* d_ws, size_t ws_size,
                              hipStream_t stream)
{
  (void)in_sizes; (void)n_in; (void)out_size; (void)ws_size;
  const float* a        = (const float*)d_in[0];
  const float* s        = (const float*)d_in[1];
  const float* z        = (const float*)d_in[2];
  const float* apb_gamma= (const float*)d_in[3];
  const float* apb_Wg   = (const float*)d_in[4];
  const float* apb_bg   = (const float*)d_in[5];
  const float* apb_Wskip= (const float*)d_in[6];
  const float* Wq       = (const float*)d_in[7];
  const float* bq       = (const float*)d_in[8];
  const float* Wk       = (const float*)d_in[9];
  const float* Wv       = (const float*)d_in[10];
  const float* Wgate    = (const float*)d_in[11];
  const float* Wo       = (const float*)d_in[12];
  const float* gamma_z  = (const float*)d_in[13];
  const float* Wz       = (const float*)d_in[14];
  const float* Wsl      = (const float*)d_in[15];
  const float* bsl      = (const float*)d_in[16];
  const float* ct_gamma = (const float*)d_in[17];
  const float* ct_Wg    = (const float*)d_in[18];
  const float* ct_bg    = (const float*)d_in[19];
  const float* ct_Wskip = (const float*)d_in[20];
  const float* Wa1      = (const float*)d_in[21];
  const float* Wa2      = (const float*)d_in[22];
  const float* Wb       = (const float*)d_in[23];
  const float* Wss      = (const float*)d_in[24];
  const float* bss      = (const float*)d_in[25];

  f16* W0 = (f16*)d_ws;
  const size_t SL = (size_t)32768*128;
  f16* an = W0 + 0*SL;   f16* qv = an;   // q overwrites a_n (dead after adaLN)
  f16* sn = W0 + 1*SL;   f16* kv = sn;   // k overwrites s_n
  f16* sh = W0 + 2*SL;   f16* vt = sh;   // v^T overwrites s_h
  f16* a1 = W0 + 3*SL;   f16* ov = a1;   // o overwrites a1
  f16* a3 = W0 + 4*SL;
  f16* gl = W0 + 5*SL;
  f16* gs = W0 + 6*SL;
  f16* gv = W0 + 7*SL;
  f16* tv = W0 + 8*SL;                    // occupies 2 slots (32768 x 256)
  f16* wA  = W0 + 10*SL;
  f16* wC  = wA  + 256*128;
  f16* wQK = wC  + 256*128;
  f16* wVG = wQK + 256*128;
  f16* wSG = wVG + 256*128;
  f16* wAB = wSG + 256*128;
  f16* wO  = wAB + 512*128;
  f16* wBt = wO  + 128*128;
  float* wzg = (float*)(wBt + 128*256);

  k_prep<<<dim3(64),256,0,stream>>>(apb_gamma,apb_Wg,apb_Wskip, ct_gamma,ct_Wg,ct_Wskip,
      Wq,Wk,Wv,Wgate, Wsl,Wss, Wa1,Wa2, Wo,Wb, gamma_z,Wz,
      wA,wC,wQK,wVG,wSG,wAB,wO,wBt,wzg);
  k_ln<<<dim3(8192),256,0,stream>>>(a,s,an,sn,sh);
  k_gemm256<0><<<dim3(128,8),256,0,stream>>>(sn,wA,apb_bg,nullptr,an,a1,nullptr);
  k_gemm256<0><<<dim3(128,8),256,0,stream>>>(sn,wC,ct_bg,nullptr,an,a3,nullptr);
  k_gemm256<1><<<dim3(128,8),256,0,stream>>>(sh,wSG,bsl,bss,nullptr,gl,gs);
  k_gemm256<2><<<dim3(128,8),256,0,stream>>>(a1,wQK,bq,nullptr,nullptr,qv,kv);
  k_gemm256<3><<<dim3(128,8),256,0,stream>>>(a1,wVG,nullptr,nullptr,nullptr,vt,gv);
  k_ab<<<dim3(128,16),256,0,stream>>>(a3,wAB,tv);
  k_attn<<<dim3(1024),512,0,stream>>>(qv,kv,vt,z,wzg,ov);
  k_final<<<dim3(128,4),256,0,stream>>>(gv,ov,tv,wO,wBt,gl,gs,(float*)d_out);
}

// Round 2
// 602.357 us; speedup vs baseline: 1.0135x; 1.0135x over previous
//
#include <hip/hip_runtime.h>

typedef _Float16 f16;
typedef f16 f16x8 __attribute__((ext_vector_type(8)));
typedef f16 f16x4 __attribute__((ext_vector_type(4)));
typedef f16 f16x2 __attribute__((ext_vector_type(2)));
typedef float f32x4 __attribute__((ext_vector_type(4)));

#define MFMA16(a,b,c) __builtin_amdgcn_mfma_f32_16x16x32_f16((a),(b),(c),0,0,0)

static __device__ __forceinline__ f16x8 ld8(const f16* p){ return *(const f16x8*)p; }
static __device__ __forceinline__ float sigm(float x){ return 1.f/(1.f + __expf(-x)); }

// ---------------------------------------------------------------------------
// Weight prep: fold gammas, cast fp16, store transposed (N rows x K cols) so
// B-fragments are contiguous 16B along K. Wa1/Wa2 interleaved by column pairs.
// ---------------------------------------------------------------------------
__global__ __launch_bounds__(256) void k_prep(
    const float* __restrict__ apb_gamma, const float* __restrict__ apb_Wg, const float* __restrict__ apb_Wskip,
    const float* __restrict__ ct_gamma,  const float* __restrict__ ct_Wg,  const float* __restrict__ ct_Wskip,
    const float* __restrict__ Wq, const float* __restrict__ Wk, const float* __restrict__ Wv, const float* __restrict__ Wgate,
    const float* __restrict__ Wsl, const float* __restrict__ Wss,
    const float* __restrict__ Wa1, const float* __restrict__ Wa2,
    const float* __restrict__ Wo, const float* __restrict__ Wb,
    const float* __restrict__ gamma_z, const float* __restrict__ Wz,
    f16* __restrict__ wA, f16* __restrict__ wC, f16* __restrict__ wQK, f16* __restrict__ wVG,
    f16* __restrict__ wSG, f16* __restrict__ wAB, f16* __restrict__ wO, f16* __restrict__ wBt,
    float* __restrict__ wzg)
{
  const int t0 = blockIdx.x*256 + threadIdx.x;
  const int stride = gridDim.x*256;
  for (int i = t0; i < 256*128; i += stride){
    const int n = i >> 7, k = i & 127;
    const int m = n & 127;
    wA[i]  = (f16)(((n<128) ? apb_Wg[k*128+m] : apb_Wskip[k*128+m]) * apb_gamma[k]);
    wC[i]  = (f16)(((n<128) ? ct_Wg[k*128+m]  : ct_Wskip[k*128+m])  * ct_gamma[k]);
    wQK[i] = (f16)((n<128) ? Wq[k*128+m] : Wk[k*128+m]);
    wVG[i] = (f16)((n<128) ? Wv[k*128+m] : Wgate[k*128+m]);
    wSG[i] = (f16)((n<128) ? Wsl[k*128+m] : Wss[k*128+m]);
  }
  for (int i = t0; i < 512*128; i += stride){
    const int n = i >> 7, k = i & 127;
    wAB[i] = (f16)((n & 1) ? Wa2[k*256 + (n>>1)] : Wa1[k*256 + (n>>1)]);
  }
  for (int i = t0; i < 128*128; i += stride){
    const int n = i >> 7, k = i & 127;
    wO[i] = (f16)Wo[k*128+n];
  }
  for (int i = t0; i < 128*256; i += stride){
    const int n = i >> 8, k = i & 255;
    wBt[i] = (f16)Wb[k*128+n];
  }
  if (t0 < 64) wzg[t0] = gamma_z[t0 & 15] * Wz[(t0 & 15)*4 + (t0 >> 4)];
}

// ---------------------------------------------------------------------------
// LayerNorm of a and s (fp32 stats), plus fp16 copy of raw s.
// ---------------------------------------------------------------------------
__global__ __launch_bounds__(256) void k_ln(const float* __restrict__ A, const float* __restrict__ S,
    f16* __restrict__ An, f16* __restrict__ Sn, f16* __restrict__ Sh)
{
  const int w = threadIdx.x >> 6, l = threadIdx.x & 63;
  const size_t row = (size_t)blockIdx.x*4 + w;
  const float2 av = *(const float2*)(A + row*128 + l*2);
  const float2 sv = *(const float2*)(S + row*128 + l*2);
  float sa = av.x + av.y, qa = av.x*av.x + av.y*av.y;
  float ss = sv.x + sv.y, qs = sv.x*sv.x + sv.y*sv.y;
  #pragma unroll
  for (int o = 32; o; o >>= 1){
    sa += __shfl_xor(sa, o); qa += __shfl_xor(qa, o);
    ss += __shfl_xor(ss, o); qs += __shfl_xor(qs, o);
  }
  const float ma = sa*(1.f/128.f), va = qa*(1.f/128.f) - ma*ma;
  const float ms = ss*(1.f/128.f), vs = qs*(1.f/128.f) - ms*ms;
  const float ra = rsqrtf(va + 1e-5f), rs = rsqrtf(vs + 1e-5f);
  f16x2 o1; o1[0] = (f16)((av.x-ma)*ra); o1[1] = (f16)((av.y-ma)*ra);
  *(f16x2*)(An + row*128 + l*2) = o1;
  f16x2 o2; o2[0] = (f16)((sv.x-ms)*rs); o2[1] = (f16)((sv.y-ms)*rs);
  *(f16x2*)(Sn + row*128 + l*2) = o2;
  f16x2 o3; o3[0] = (f16)sv.x; o3[1] = (f16)sv.y;
  *(f16x2*)(Sh + row*128 + l*2) = o3;
}

// ---------------------------------------------------------------------------
// Fused dual adaLN: A1 = sigmoid(sn@WgA + bA)*an + sn@WskipA  (gamma folded),
//                   A3 = same with ct weights. One pass over sn/an.
// ---------------------------------------------------------------------------
__global__ __launch_bounds__(256) void k_adaln(
    const f16* __restrict__ Sn, const f16* __restrict__ An,
    const f16* __restrict__ wA, const f16* __restrict__ wC,
    const float* __restrict__ bgA, const float* __restrict__ bgC,
    f16* __restrict__ A1, f16* __restrict__ A3)
{
  const int l = threadIdx.x & 63, w = threadIdx.x >> 6;
  const int c = l & 15, q4 = l >> 4;
  const int n0 = blockIdx.y * 16;
  f16x8 bA0[4], bA1[4], bC0[4], bC1[4];
  #pragma unroll
  for (int kc = 0; kc < 4; kc++){
    bA0[kc] = ld8(wA + (size_t)(n0 + c)*128 + kc*32 + q4*8);
    bA1[kc] = ld8(wA + (size_t)(128 + n0 + c)*128 + kc*32 + q4*8);
    bC0[kc] = ld8(wC + (size_t)(n0 + c)*128 + kc*32 + q4*8);
    bC1[kc] = ld8(wC + (size_t)(128 + n0 + c)*128 + kc*32 + q4*8);
  }
  const float bvA = bgA[n0 + c], bvC = bgC[n0 + c];
  for (int mi = 0; mi < 4; mi++){
    const int mbase = blockIdx.x*256 + w*64 + mi*16;
    const f16* xp = Sn + (size_t)(mbase + c)*128 + q4*8;
    f32x4 dA0 = {0,0,0,0}, dA1 = {0,0,0,0}, dC0 = {0,0,0,0}, dC1 = {0,0,0,0};
    #pragma unroll
    for (int kc = 0; kc < 4; kc++){
      f16x8 av = ld8(xp + kc*32);
      dA0 = MFMA16(av, bA0[kc], dA0);
      dA1 = MFMA16(av, bA1[kc], dA1);
      dC0 = MFMA16(av, bC0[kc], dC0);
      dC1 = MFMA16(av, bC1[kc], dC1);
    }
    #pragma unroll
    for (int r = 0; r < 4; r++){
      const size_t row = mbase + q4*4 + r;
      const float anv = (float)An[row*128 + n0 + c];
      A1[row*128 + n0 + c] = (f16)(sigm(dA0[r] + bvA)*anv + dA1[r]);
      A3[row*128 + n0 + c] = (f16)(sigm(dC0[r] + bvC)*anv + dC1[r]);
    }
  }
}

// ---------------------------------------------------------------------------
// Gates: gl = sigmoid(s@Wsl + bsl), gs = sigmoid(s@Wss + bss)
// ---------------------------------------------------------------------------
__global__ __launch_bounds__(256) void k_gates(
    const f16* __restrict__ X, const f16* __restrict__ Wt,
    const float* __restrict__ bias0, const float* __restrict__ bias1,
    f16* __restrict__ out0, f16* __restrict__ out1)
{
  const int l = threadIdx.x & 63, w = threadIdx.x >> 6;
  const int c = l & 15, q4 = l >> 4;
  const int n0 = blockIdx.y * 16;
  f16x8 b0[4], b1[4];
  #pragma unroll
  for (int kc = 0; kc < 4; kc++){
    b0[kc] = ld8(Wt + (size_t)(n0 + c)*128 + kc*32 + q4*8);
    b1[kc] = ld8(Wt + (size_t)(128 + n0 + c)*128 + kc*32 + q4*8);
  }
  const float bv0 = bias0[n0 + c], bv1 = bias1[n0 + c];
  for (int mi = 0; mi < 4; mi++){
    const int mbase = blockIdx.x*256 + w*64 + mi*16;
    const f16* xp = X + (size_t)(mbase + c)*128 + q4*8;
    f32x4 d0 = {0,0,0,0}, d1 = {0,0,0,0};
    #pragma unroll
    for (int kc = 0; kc < 4; kc++){
      f16x8 av = ld8(xp + kc*32);
      d0 = MFMA16(av, b0[kc], d0);
      d1 = MFMA16(av, b1[kc], d1);
    }
    #pragma unroll
    for (int r = 0; r < 4; r++){
      const size_t row = mbase + q4*4 + r;
      out0[row*128 + n0 + c] = (f16)sigm(d0[r] + bv0);
      out1[row*128 + n0 + c] = (f16)sigm(d1[r] + bv1);
    }
  }
}

// ---------------------------------------------------------------------------
// Fused QKVG: q = (a1@Wq+bq)/sqrt(32), k = a1@Wk, v^T[b][c][n], g = sigm(a1@Wgate)
// One pass over a1.
// ---------------------------------------------------------------------------
__global__ __launch_bounds__(256) void k_qkvg(
    const f16* __restrict__ X, const f16* __restrict__ wQK, const f16* __restrict__ wVG,
    const float* __restrict__ bq,
    f16* __restrict__ Qo, f16* __restrict__ Ko, f16* __restrict__ Vt, f16* __restrict__ Go)
{
  const int l = threadIdx.x & 63, w = threadIdx.x >> 6;
  const int c = l & 15, q4 = l >> 4;
  const int n0 = blockIdx.y * 16;
  f16x8 bQ[4], bK[4], bV[4], bG[4];
  #pragma unroll
  for (int kc = 0; kc < 4; kc++){
    bQ[kc] = ld8(wQK + (size_t)(n0 + c)*128 + kc*32 + q4*8);
    bK[kc] = ld8(wQK + (size_t)(128 + n0 + c)*128 + kc*32 + q4*8);
    bV[kc] = ld8(wVG + (size_t)(n0 + c)*128 + kc*32 + q4*8);
    bG[kc] = ld8(wVG + (size_t)(128 + n0 + c)*128 + kc*32 + q4*8);
  }
  const float bvq = bq[n0 + c];
  for (int mi = 0; mi < 4; mi++){
    const int mbase = blockIdx.x*256 + w*64 + mi*16;
    const f16* xp = X + (size_t)(mbase + c)*128 + q4*8;
    f32x4 dQ = {0,0,0,0}, dK = {0,0,0,0}, dV = {0,0,0,0}, dG = {0,0,0,0};
    #pragma unroll
    for (int kc = 0; kc < 4; kc++){
      f16x8 av = ld8(xp + kc*32);
      dQ = MFMA16(av, bQ[kc], dQ);
      dK = MFMA16(av, bK[kc], dK);
      dV = MFMA16(av, bV[kc], dV);
      dG = MFMA16(av, bG[kc], dG);
    }
    #pragma unroll
    for (int r = 0; r < 4; r++){
      const size_t row = mbase + q4*4 + r;
      Qo[row*128 + n0 + c] = (f16)((dQ[r] + bvq)*0.17677669529663687f);
      Ko[row*128 + n0 + c] = (f16)dK[r];
      Go[row*128 + n0 + c] = (f16)sigm(dG[r]);
    }
    f16x4 vv;
    #pragma unroll
    for (int r = 0; r < 4; r++) vv[r] = (f16)dV[r];
    const int bidx = mbase >> 14;
    const int ntk  = (mbase & 16383) + q4*4;
    *(f16x4*)(Vt + ((size_t)bidx*128 + n0 + c)*16384 + ntk) = vv;
  }
}

// ---------------------------------------------------------------------------
// Transition: t = silu(a3@Wa1) * (a3@Wa2), interleaved weights, shfl_xor pair.
// ---------------------------------------------------------------------------
__global__ __launch_bounds__(256) void k_ab(const f16* __restrict__ X, const f16* __restrict__ Wt,
                                            f16* __restrict__ T)
{
  const int l = threadIdx.x & 63, w = threadIdx.x >> 6;
  const int c = l & 15, q4 = l >> 4;
  const int n0 = blockIdx.y * 32;
  f16x8 b0[4], b1[4];
  #pragma unroll
  for (int kc = 0; kc < 4; kc++){
    b0[kc] = ld8(Wt + (size_t)(n0 + c)*128 + kc*32 + q4*8);
    b1[kc] = ld8(Wt + (size_t)(n0 + 16 + c)*128 + kc*32 + q4*8);
  }
  for (int mi = 0; mi < 4; mi++){
    const int mbase = blockIdx.x*256 + w*64 + mi*16;
    const f16* xp = X + (size_t)(mbase + c)*128 + q4*8;
    f32x4 d0 = {0,0,0,0}, d1 = {0,0,0,0};
    #pragma unroll
    for (int kc = 0; kc < 4; kc++){
      f16x8 av = ld8(xp + kc*32);
      d0 = MFMA16(av, b0[kc], d0);
      d1 = MFMA16(av, b1[kc], d1);
    }
    #pragma unroll
    for (int tile = 0; tile < 2; tile++){
      #pragma unroll
      for (int r = 0; r < 4; r++){
        const float dv = tile ? d1[r] : d0[r];
        const float ov = __shfl_xor(dv, 1);
        const float u  = (c & 1) ? ov : dv;
        const float vv = (c & 1) ? dv : ov;
        const float tvv = (u * sigm(u)) * vv;
        if (!(c & 1)){
          const size_t row = mbase + q4*4 + r;
          T[row*256 + ((n0 + tile*16 + c) >> 1)] = (f16)tvv;
        }
      }
    }
  }
}

// ---------------------------------------------------------------------------
// Fused windowed attention, z-bias in-kernel. One block per (b, nb); 8 waves.
// K and V^T fragments read DIRECTLY from global (L2-resident, 75% window
// overlap between adjacent blocks) — LDS only for the bias/P tile (~35 KB)
// so 3-4 blocks/CU instead of 1.
// ---------------------------------------------------------------------------
__global__ __launch_bounds__(512) void k_attn(const f16* __restrict__ Q, const f16* __restrict__ K,
    const f16* __restrict__ VT, const float* __restrict__ Z, const float* __restrict__ WZG,
    f16* __restrict__ Og)
{
  __shared__ f16 upb[17408];        // phase1: bias[4][32][132]; phase2: p[8][16][136]
  __shared__ float wzg_s[64];
  const int tid = threadIdx.x;
  const int b = blockIdx.x >> 9, nb = blockIdx.x & 511;
  if (tid < 64) wzg_s[tid] = WZG[tid];
  __syncthreads();
  // z -> LN -> @ (gamma_z . Wz) -> bias tile in LDS (fp16)
  #pragma unroll
  for (int i = 0; i < 8; i++){
    const int p  = tid + i*512;
    const int qq = p >> 7, kk = p & 127;
    const float* zp = Z + ((((size_t)b*512 + nb)*32 + qq)*128 + kk)*16;
    const float4 z0 = *(const float4*)(zp);
    const float4 z1 = *(const float4*)(zp + 4);
    const float4 z2 = *(const float4*)(zp + 8);
    const float4 z3 = *(const float4*)(zp + 12);
    const float xs[16] = {z0.x,z0.y,z0.z,z0.w, z1.x,z1.y,z1.z,z1.w,
                          z2.x,z2.y,z2.z,z2.w, z3.x,z3.y,z3.z,z3.w};
    float sm = 0.f, sq = 0.f;
    #pragma unroll
    for (int cc = 0; cc < 16; cc++){ sm += xs[cc]; sq += xs[cc]*xs[cc]; }
    const float mean = sm*(1.f/16.f);
    const float var  = sq*(1.f/16.f) - mean*mean;
    const float rs   = rsqrtf(var + 1e-5f);
    #pragma unroll
    for (int h = 0; h < 4; h++){
      float acc = 0.f;
      #pragma unroll
      for (int cc = 0; cc < 16; cc++) acc += (xs[cc]-mean)*wzg_s[h*16+cc];
      upb[(h*32 + qq)*132 + kk] = (f16)(acc*rs);
    }
  }
  __syncthreads();

  const int l = tid & 63, w = tid >> 6;
  const int c = l & 15, q4 = l >> 4;
  const int h = w >> 1, qh = w & 1, m0 = qh*16;
  const f16x8 aq = ld8(Q + ((size_t)b*16384 + (size_t)nb*32 + m0 + c)*128 + h*32 + q4*8);
  const long kbase = (long)b*16384 + (long)nb*32 - 48;   // OOB stays inside ws: finite garbage, masked
  f32x4 sc[8];
  #pragma unroll
  for (int nt = 0; nt < 8; nt++){
    const f16x8 bf = ld8(K + (kbase + nt*16 + c)*128 + h*32 + q4*8);
    f32x4 zz = {0.f,0.f,0.f,0.f};
    sc[nt] = MFMA16(aq, bf, zz);
  }
  #pragma unroll
  for (int nt = 0; nt < 8; nt++){
    const int key = nt*16 + c;
    const long kt = (long)nb*32 - 48 + key;
    const bool inv = (kt < 0) || (kt >= 16384);
    #pragma unroll
    for (int r = 0; r < 4; r++){
      const float v = sc[nt][r] + (float)upb[(h*32 + m0 + q4*4 + r)*132 + key];
      sc[nt][r] = inv ? -1e9f : v;
    }
  }
  // softmax over 128 keys per row
  #pragma unroll
  for (int r = 0; r < 4; r++){
    float mx = sc[0][r];
    #pragma unroll
    for (int nt = 1; nt < 8; nt++) mx = fmaxf(mx, sc[nt][r]);
    #pragma unroll
    for (int o = 8; o; o >>= 1) mx = fmaxf(mx, __shfl_xor(mx, o));
    float sum = 0.f;
    #pragma unroll
    for (int nt = 0; nt < 8; nt++){ const float e = __expf(sc[nt][r]-mx); sc[nt][r] = e; sum += e; }
    #pragma unroll
    for (int o = 8; o; o >>= 1) sum += __shfl_xor(sum, o);
    const float inv = 1.f/sum;
    #pragma unroll
    for (int nt = 0; nt < 8; nt++) sc[nt][r] *= inv;
  }
  __syncthreads();   // all bias reads done -> reuse upb as P
  #pragma unroll
  for (int nt = 0; nt < 8; nt++)
    #pragma unroll
    for (int r = 0; r < 4; r++)
      upb[(w*16 + q4*4 + r)*136 + nt*16 + c] = (f16)sc[nt][r];
  // O = P @ V, V^T fragments direct from global
  const f16* vb = VT + ((long)b*128)*16384 + (long)nb*32 - 48;
  f32x4 o0 = {0.f,0.f,0.f,0.f}, o1 = {0.f,0.f,0.f,0.f};
  #pragma unroll
  for (int kc = 0; kc < 4; kc++){
    const f16x8 pa = *(const f16x8*)&upb[(w*16 + c)*136 + kc*32 + q4*8];
    const f16x8 v0 = ld8(vb + (long)(h*32 + c)*16384 + kc*32 + q4*8);
    const f16x8 v1 = ld8(vb + (long)(h*32 + 16 + c)*16384 + kc*32 + q4*8);
    o0 = MFMA16(pa, v0, o0);
    o1 = MFMA16(pa, v1, o1);
  }
  #pragma unroll
  for (int r = 0; r < 4; r++){
    const size_t tok = (size_t)b*16384 + (size_t)nb*32 + m0 + q4*4 + r;
    Og[tok*128 + h*32 + c]      = (f16)o0[r];
    Og[tok*128 + h*32 + 16 + c] = (f16)o1[r];
  }
}

// ---------------------------------------------------------------------------
// Final: out = gl * ((g.o) @ Wo) + gs * (t @ Wb).  Wo: K=128, Wb: K=256.
// ---------------------------------------------------------------------------
__global__ __launch_bounds__(256) void k_final(const f16* __restrict__ G, const f16* __restrict__ O,
    const f16* __restrict__ T, const f16* __restrict__ Wot, const f16* __restrict__ Wbt,
    const f16* __restrict__ GL, const f16* __restrict__ GS, float* __restrict__ out)
{
  const int l = threadIdx.x & 63, w = threadIdx.x >> 6;
  const int c = l & 15, q4 = l >> 4;
  #pragma unroll
  for (int nt = 0; nt < 2; nt++){
    const int cb = blockIdx.y*32 + nt*16;
    f16x8 bo[4], bb[8];
    #pragma unroll
    for (int kc = 0; kc < 4; kc++) bo[kc] = ld8(Wot + (size_t)(cb + c)*128 + kc*32 + q4*8);
    #pragma unroll
    for (int kc = 0; kc < 8; kc++) bb[kc] = ld8(Wbt + (size_t)(cb + c)*256 + kc*32 + q4*8);
    for (int mi = 0; mi < 4; mi++){
      const int mbase = blockIdx.x*256 + w*64 + mi*16;
      f32x4 d1 = {0.f,0.f,0.f,0.f}, d2 = {0.f,0.f,0.f,0.f};
      const f16* gp = G + (size_t)(mbase + c)*128 + q4*8;
      const f16* op = O + (size_t)(mbase + c)*128 + q4*8;
      #pragma unroll
      for (int kc = 0; kc < 4; kc++){
        const f16x8 av = ld8(gp + kc*32) * ld8(op + kc*32);
        d1 = MFMA16(av, bo[kc], d1);
      }
      const f16* tp = T + (size_t)(mbase + c)*256 + q4*8;
      #pragma unroll
      for (int kc = 0; kc < 8; kc++) d2 = MFMA16(ld8(tp + kc*32), bb[kc], d2);
      #pragma unroll
      for (int r = 0; r < 4; r++){
        const size_t row = mbase + q4*4 + r;
        const float glv = (float)GL[row*128 + cb + c];
        const float gsv = (float)GS[row*128 + cb + c];
        out[row*128 + cb + c] = glv*d1[r] + gsv*d2[r];
      }
    }
  }
}

// ---------------------------------------------------------------------------
extern "C" void kernel_launch(void* const* d_in, const int* in_sizes, int n_in,
                              void* d_out, int out_size, void* d_ws, size_t ws_size,
                              hipStream_t stream)
{
  (void)in_sizes; (void)n_in; (void)out_size; (void)ws_size;
  const float* a        = (const float*)d_in[0];
  const float* s        = (const float*)d_in[1];
  const float* z        = (const float*)d_in[2];
  const float* apb_gamma= (const float*)d_in[3];
  const float* apb_Wg   = (const float*)d_in[4];
  const float* apb_bg   = (const float*)d_in[5];
  const float* apb_Wskip= (const float*)d_in[6];
  const float* Wq       = (const float*)d_in[7];
  const float* bq       = (const float*)d_in[8];
  const float* Wk       = (const float*)d_in[9];
  const float* Wv       = (const float*)d_in[10];
  const float* Wgate    = (const float*)d_in[11];
  const float* Wo       = (const float*)d_in[12];
  const float* gamma_z  = (const float*)d_in[13];
  const float* Wz       = (const float*)d_in[14];
  const float* Wsl      = (const float*)d_in[15];
  const float* bsl      = (const float*)d_in[16];
  const float* ct_gamma = (const float*)d_in[17];
  const float* ct_Wg    = (const float*)d_in[18];
  const float* ct_bg    = (const float*)d_in[19];
  const float* ct_Wskip = (const float*)d_in[20];
  const float* Wa1      = (const float*)d_in[21];
  const float* Wa2      = (const float*)d_in[22];
  const float* Wb       = (const float*)d_in[23];
  const float* Wss      = (const float*)d_in[24];
  const float* bss      = (const float*)d_in[25];

  f16* W0 = (f16*)d_ws;
  const size_t SL = (size_t)32768*128;
  f16* an = W0 + 0*SL;   f16* qv = an;   // q overwrites a_n (dead after adaLN)
  f16* sn = W0 + 1*SL;   f16* kv = sn;   // k overwrites s_n
  f16* sh = W0 + 2*SL;   f16* vt = sh;   // v^T overwrites s_h (dead after gates)
  f16* a1 = W0 + 3*SL;   f16* ov = a1;   // o overwrites a1
  f16* a3 = W0 + 4*SL;
  f16* gl = W0 + 5*SL;
  f16* gs = W0 + 6*SL;
  f16* gv = W0 + 7*SL;
  f16* tv = W0 + 8*SL;                    // occupies 2 slots (32768 x 256)
  f16* wA  = W0 + 10*SL;
  f16* wC  = wA  + 256*128;
  f16* wQK = wC  + 256*128;
  f16* wVG = wQK + 256*128;
  f16* wSG = wVG + 256*128;
  f16* wAB = wSG + 256*128;
  f16* wO  = wAB + 512*128;
  f16* wBt = wO  + 128*128;
  float* wzg = (float*)(wBt + 128*256);

  k_prep<<<dim3(64),256,0,stream>>>(apb_gamma,apb_Wg,apb_Wskip, ct_gamma,ct_Wg,ct_Wskip,
      Wq,Wk,Wv,Wgate, Wsl,Wss, Wa1,Wa2, Wo,Wb, gamma_z,Wz,
      wA,wC,wQK,wVG,wSG,wAB,wO,wBt,wzg);
  k_ln<<<dim3(8192),256,0,stream>>>(a,s,an,sn,sh);
  k_adaln<<<dim3(128,8),256,0,stream>>>(sn,an,wA,wC,apb_bg,ct_bg,a1,a3);
  k_gates<<<dim3(128,8),256,0,stream>>>(sh,wSG,bsl,bss,gl,gs);
  k_qkvg<<<dim3(128,8),256,0,stream>>>(a1,wQK,wVG,bq,qv,kv,vt,gv);
  k_ab<<<dim3(128,16),256,0,stream>>>(a3,wAB,tv);
  k_attn<<<dim3(1024),512,0,stream>>>(qv,kv,vt,z,wzg,ov);
  k_final<<<dim3(128,4),256,0,stream>>>(gv,ov,tv,wO,wBt,gl,gs,(float*)d_out);
}

// Round 3
// 534.910 us; speedup vs baseline: 1.1413x; 1.1261x over previous
//
#include <hip/hip_runtime.h>

typedef _Float16 f16;
typedef f16 f16x8 __attribute__((ext_vector_type(8)));
typedef f16 f16x4 __attribute__((ext_vector_type(4)));
typedef f16 f16x2 __attribute__((ext_vector_type(2)));
typedef float f32x4 __attribute__((ext_vector_type(4)));

#define MFMA16(a,b,c) __builtin_amdgcn_mfma_f32_16x16x32_f16((a),(b),(c),0,0,0)

static __device__ __forceinline__ f16x8 ld8(const f16* p){ return *(const f16x8*)p; }
static __device__ __forceinline__ float sigm(float x){ return 1.f/(1.f + __expf(-x)); }

// ---------------------------------------------------------------------------
// Weight prep: fold gammas, cast fp16, store transposed (N rows x K cols) so
// B-fragments are contiguous 16B along K. Also colsums of Wsl/Wss for the
// raw-s gate un-normalization trick, and the fused gamma_z*Wz vector.
// ---------------------------------------------------------------------------
__global__ __launch_bounds__(256) void k_prep(
    const float* __restrict__ apb_gamma, const float* __restrict__ apb_Wg, const float* __restrict__ apb_Wskip,
    const float* __restrict__ ct_gamma,  const float* __restrict__ ct_Wg,  const float* __restrict__ ct_Wskip,
    const float* __restrict__ Wq, const float* __restrict__ Wk, const float* __restrict__ Wv, const float* __restrict__ Wgate,
    const float* __restrict__ Wsl, const float* __restrict__ Wss,
    const float* __restrict__ Wa1, const float* __restrict__ Wa2,
    const float* __restrict__ Wo, const float* __restrict__ Wb,
    const float* __restrict__ gamma_z, const float* __restrict__ Wz,
    f16* __restrict__ wA, f16* __restrict__ wC, f16* __restrict__ wQK, f16* __restrict__ wVG,
    f16* __restrict__ wSG, f16* __restrict__ wAB, f16* __restrict__ wO, f16* __restrict__ wBt,
    float* __restrict__ wzg, float* __restrict__ Slv, float* __restrict__ Ssv)
{
  const int t0 = blockIdx.x*256 + threadIdx.x;
  const int stride = gridDim.x*256;
  for (int i = t0; i < 256*128; i += stride){
    const int n = i >> 7, k = i & 127;
    const int m = n & 127;
    wA[i]  = (f16)(((n<128) ? apb_Wg[k*128+m] : apb_Wskip[k*128+m]) * apb_gamma[k]);
    wC[i]  = (f16)(((n<128) ? ct_Wg[k*128+m]  : ct_Wskip[k*128+m])  * ct_gamma[k]);
    wQK[i] = (f16)((n<128) ? Wq[k*128+m] : Wk[k*128+m]);
    wVG[i] = (f16)((n<128) ? Wv[k*128+m] : Wgate[k*128+m]);
    wSG[i] = (f16)((n<128) ? Wsl[k*128+m] : Wss[k*128+m]);
  }
  for (int i = t0; i < 512*128; i += stride){
    const int n = i >> 7, k = i & 127;
    wAB[i] = (f16)((n < 256) ? Wa1[k*256 + n] : Wa2[k*256 + (n-256)]);
  }
  for (int i = t0; i < 128*128; i += stride){
    const int n = i >> 7, k = i & 127;
    wO[i] = (f16)Wo[k*128+n];
  }
  for (int i = t0; i < 128*256; i += stride){
    const int n = i >> 8, k = i & 255;
    wBt[i] = (f16)Wb[k*128+n];
  }
  if (t0 < 64) wzg[t0] = gamma_z[t0 & 15] * Wz[(t0 & 15)*4 + (t0 >> 4)];
  if (t0 < 256){
    const int cc = t0 & 127;
    const float* Wp = (t0 >= 128) ? Wss : Wsl;
    float acc = 0.f;
    for (int k = 0; k < 128; k++) acc += Wp[k*128 + cc];
    if (t0 >= 128) Ssv[cc] = acc; else Slv[cc] = acc;
  }
}

// ---------------------------------------------------------------------------
// MEGA-FUSED pre-attention kernel. 64 rows per block, 256 threads (4 waves).
// Phase 1: LN(a), LN(s) -> LDS (f16) + per-row s mean/std.
// Phase 2: dual adaLN -> a1, a3 in LDS.
// Phase 3: QKVG (from a1), transition t (from a3), gates gl/gs (from sn,
//          un-normalized via std/mean + colsum). Outputs straight to global.
// LDS ~70 KB -> 2 blocks/CU. Weights stay hot in L1/L2.
// ---------------------------------------------------------------------------
__global__ __launch_bounds__(256) void k_pre(
    const float* __restrict__ A, const float* __restrict__ S,
    const f16* __restrict__ wA, const f16* __restrict__ wC,
    const f16* __restrict__ wQK, const f16* __restrict__ wVG,
    const f16* __restrict__ wSG, const f16* __restrict__ wAB,
    const float* __restrict__ bgA, const float* __restrict__ bgC,
    const float* __restrict__ bq, const float* __restrict__ bsl, const float* __restrict__ bss,
    const float* __restrict__ Slv, const float* __restrict__ Ssv,
    f16* __restrict__ Qo, f16* __restrict__ Ko, f16* __restrict__ Vt, f16* __restrict__ Go,
    f16* __restrict__ T, f16* __restrict__ GL, f16* __restrict__ GS)
{
  __shared__ f16 lsn[64*136];
  __shared__ f16 lan[64*136];
  __shared__ f16 la1[64*136];
  __shared__ f16 la3[64*136];
  __shared__ float lsm[64], lsd[64];
  const int tid = threadIdx.x;
  const size_t rbase = (size_t)blockIdx.x * 64;

  // ---- Phase 1: LayerNorm ----
  {
    const int row = tid >> 2, part = tid & 3;
    const size_t gr = rbase + row;
    // s
    {
      const float* sp = S + gr*128 + part*32;
      float v[32];
      #pragma unroll
      for (int j = 0; j < 8; j++){
        const float4 t4 = ((const float4*)sp)[j];
        v[j*4+0]=t4.x; v[j*4+1]=t4.y; v[j*4+2]=t4.z; v[j*4+3]=t4.w;
      }
      float sm = 0.f, sq = 0.f;
      #pragma unroll
      for (int j = 0; j < 32; j++){ sm += v[j]; sq += v[j]*v[j]; }
      sm += __shfl_xor(sm,1); sq += __shfl_xor(sq,1);
      sm += __shfl_xor(sm,2); sq += __shfl_xor(sq,2);
      const float mean = sm*(1.f/128.f);
      const float var  = sq*(1.f/128.f) - mean*mean;
      const float rstd = rsqrtf(var + 1e-5f);
      if (part == 0){ lsm[row] = mean; lsd[row] = (var + 1e-5f)*rstd; }  // std
      #pragma unroll
      for (int j = 0; j < 4; j++){
        f16x8 o;
        #pragma unroll
        for (int e = 0; e < 8; e++) o[e] = (f16)((v[j*8+e]-mean)*rstd);
        *(f16x8*)&lsn[row*136 + part*32 + j*8] = o;
      }
    }
    // a
    {
      const float* ap = A + gr*128 + part*32;
      float v[32];
      #pragma unroll
      for (int j = 0; j < 8; j++){
        const float4 t4 = ((const float4*)ap)[j];
        v[j*4+0]=t4.x; v[j*4+1]=t4.y; v[j*4+2]=t4.z; v[j*4+3]=t4.w;
      }
      float sm = 0.f, sq = 0.f;
      #pragma unroll
      for (int j = 0; j < 32; j++){ sm += v[j]; sq += v[j]*v[j]; }
      sm += __shfl_xor(sm,1); sq += __shfl_xor(sq,1);
      sm += __shfl_xor(sm,2); sq += __shfl_xor(sq,2);
      const float mean = sm*(1.f/128.f);
      const float var  = sq*(1.f/128.f) - mean*mean;
      const float rstd = rsqrtf(var + 1e-5f);
      #pragma unroll
      for (int j = 0; j < 4; j++){
        f16x8 o;
        #pragma unroll
        for (int e = 0; e < 8; e++) o[e] = (f16)((v[j*8+e]-mean)*rstd);
        *(f16x8*)&lan[row*136 + part*32 + j*8] = o;
      }
    }
  }
  __syncthreads();

  const int l = tid & 63, w = tid >> 6;
  const int c = l & 15, q4 = l >> 4;

  // ---- Phase 2: dual adaLN (16 wave-jobs: 8 col-tiles x {A,C}) ----
  for (int jj = 0; jj < 4; jj++){
    const int job = jj*4 + w;
    const int n0 = (job >> 1)*16;
    const int mat = job & 1;
    const f16* W = mat ? wC : wA;
    f16* dst = mat ? la3 : la1;
    const float bv = (mat ? bgC : bgA)[n0 + c];
    f16x8 b0[4], b1[4];
    #pragma unroll
    for (int kc = 0; kc < 4; kc++){
      b0[kc] = ld8(W + (size_t)(n0 + c)*128 + kc*32 + q4*8);
      b1[kc] = ld8(W + (size_t)(128 + n0 + c)*128 + kc*32 + q4*8);
    }
    for (int mi = 0; mi < 4; mi++){
      f32x4 d0 = {0,0,0,0}, d1 = {0,0,0,0};
      #pragma unroll
      for (int kc = 0; kc < 4; kc++){
        const f16x8 av = *(const f16x8*)&lsn[(mi*16 + c)*136 + kc*32 + q4*8];
        d0 = MFMA16(av, b0[kc], d0);
        d1 = MFMA16(av, b1[kc], d1);
      }
      #pragma unroll
      for (int r = 0; r < 4; r++){
        const int row = mi*16 + q4*4 + r;
        const float anv = (float)lan[row*136 + n0 + c];
        dst[row*136 + n0 + c] = (f16)(sigm(d0[r] + bv)*anv + d1[r]);
      }
    }
  }
  __syncthreads();

  // ---- Phase 3a: QKVG from a1 (8 wave-jobs) ----
  for (int jj = 0; jj < 2; jj++){
    const int n0 = (jj*4 + w)*16;
    f16x8 bQ[4], bK[4], bV[4], bG[4];
    #pragma unroll
    for (int kc = 0; kc < 4; kc++){
      bQ[kc] = ld8(wQK + (size_t)(n0 + c)*128 + kc*32 + q4*8);
      bK[kc] = ld8(wQK + (size_t)(128 + n0 + c)*128 + kc*32 + q4*8);
      bV[kc] = ld8(wVG + (size_t)(n0 + c)*128 + kc*32 + q4*8);
      bG[kc] = ld8(wVG + (size_t)(128 + n0 + c)*128 + kc*32 + q4*8);
    }
    const float bvq = bq[n0 + c];
    for (int mi = 0; mi < 4; mi++){
      f32x4 dQ = {0,0,0,0}, dK = {0,0,0,0}, dV = {0,0,0,0}, dG = {0,0,0,0};
      #pragma unroll
      for (int kc = 0; kc < 4; kc++){
        const f16x8 av = *(const f16x8*)&la1[(mi*16 + c)*136 + kc*32 + q4*8];
        dQ = MFMA16(av, bQ[kc], dQ);
        dK = MFMA16(av, bK[kc], dK);
        dV = MFMA16(av, bV[kc], dV);
        dG = MFMA16(av, bG[kc], dG);
      }
      #pragma unroll
      for (int r = 0; r < 4; r++){
        const size_t grow = rbase + mi*16 + q4*4 + r;
        Qo[grow*128 + n0 + c] = (f16)((dQ[r] + bvq)*0.17677669529663687f);
        Ko[grow*128 + n0 + c] = (f16)dK[r];
        Go[grow*128 + n0 + c] = (f16)sigm(dG[r]);
      }
      f16x4 vv;
      #pragma unroll
      for (int r = 0; r < 4; r++) vv[r] = (f16)dV[r];
      const int bidx = (int)(rbase >> 14);
      const int ntk  = (int)(rbase & 16383) + mi*16 + q4*4;
      *(f16x4*)(Vt + ((size_t)bidx*128 + n0 + c)*16384 + ntk) = vv;
    }
  }

  // ---- Phase 3b: transition t = silu(a3@Wa1) * (a3@Wa2) (16 wave-jobs) ----
  for (int jj = 0; jj < 4; jj++){
    const int n0t = (jj*4 + w)*16;
    f16x8 b1v[4], b2v[4];
    #pragma unroll
    for (int kc = 0; kc < 4; kc++){
      b1v[kc] = ld8(wAB + (size_t)(n0t + c)*128 + kc*32 + q4*8);
      b2v[kc] = ld8(wAB + (size_t)(256 + n0t + c)*128 + kc*32 + q4*8);
    }
    for (int mi = 0; mi < 4; mi++){
      f32x4 d0 = {0,0,0,0}, d1 = {0,0,0,0};
      #pragma unroll
      for (int kc = 0; kc < 4; kc++){
        const f16x8 av = *(const f16x8*)&la3[(mi*16 + c)*136 + kc*32 + q4*8];
        d0 = MFMA16(av, b1v[kc], d0);
        d1 = MFMA16(av, b2v[kc], d1);
      }
      #pragma unroll
      for (int r = 0; r < 4; r++){
        const size_t grow = rbase + mi*16 + q4*4 + r;
        const float u = d0[r];
        T[grow*256 + n0t + c] = (f16)((u*sigm(u))*d1[r]);
      }
    }
  }

  // ---- Phase 3c: gates from sn via un-normalization (8 wave-jobs) ----
  for (int jj = 0; jj < 2; jj++){
    const int n0 = (jj*4 + w)*16;
    f16x8 b0[4], b1[4];
    #pragma unroll
    for (int kc = 0; kc < 4; kc++){
      b0[kc] = ld8(wSG + (size_t)(n0 + c)*128 + kc*32 + q4*8);
      b1[kc] = ld8(wSG + (size_t)(128 + n0 + c)*128 + kc*32 + q4*8);
    }
    const float slc = Slv[n0 + c], ssc = Ssv[n0 + c];
    const float bl = bsl[n0 + c],  bs2 = bss[n0 + c];
    for (int mi = 0; mi < 4; mi++){
      f32x4 d0 = {0,0,0,0}, d1 = {0,0,0,0};
      #pragma unroll
      for (int kc = 0; kc < 4; kc++){
        const f16x8 av = *(const f16x8*)&lsn[(mi*16 + c)*136 + kc*32 + q4*8];
        d0 = MFMA16(av, b0[kc], d0);
        d1 = MFMA16(av, b1[kc], d1);
      }
      #pragma unroll
      for (int r = 0; r < 4; r++){
        const int row = mi*16 + q4*4 + r;
        const size_t grow = rbase + row;
        const float mn = lsm[row], sd = lsd[row];
        GL[grow*128 + n0 + c] = (f16)sigm(d0[r]*sd + mn*slc + bl);
        GS[grow*128 + n0 + c] = (f16)sigm(d1[r]*sd + mn*ssc + bs2);
      }
    }
  }
}

// ---------------------------------------------------------------------------
// Fused windowed attention, z-bias in-kernel (unchanged from round 2).
// ---------------------------------------------------------------------------
__global__ __launch_bounds__(512) void k_attn(const f16* __restrict__ Q, const f16* __restrict__ K,
    const f16* __restrict__ VT, const float* __restrict__ Z, const float* __restrict__ WZG,
    f16* __restrict__ Og)
{
  __shared__ f16 upb[17408];
  __shared__ float wzg_s[64];
  const int tid = threadIdx.x;
  const int b = blockIdx.x >> 9, nb = blockIdx.x & 511;
  if (tid < 64) wzg_s[tid] = WZG[tid];
  __syncthreads();
  #pragma unroll
  for (int i = 0; i < 8; i++){
    const int p  = tid + i*512;
    const int qq = p >> 7, kk = p & 127;
    const float* zp = Z + ((((size_t)b*512 + nb)*32 + qq)*128 + kk)*16;
    const float4 z0 = *(const float4*)(zp);
    const float4 z1 = *(const float4*)(zp + 4);
    const float4 z2 = *(const float4*)(zp + 8);
    const float4 z3 = *(const float4*)(zp + 12);
    const float xs[16] = {z0.x,z0.y,z0.z,z0.w, z1.x,z1.y,z1.z,z1.w,
                          z2.x,z2.y,z2.z,z2.w, z3.x,z3.y,z3.z,z3.w};
    float sm = 0.f, sq = 0.f;
    #pragma unroll
    for (int cc = 0; cc < 16; cc++){ sm += xs[cc]; sq += xs[cc]*xs[cc]; }
    const float mean = sm*(1.f/16.f);
    const float var  = sq*(1.f/16.f) - mean*mean;
    const float rs   = rsqrtf(var + 1e-5f);
    #pragma unroll
    for (int h = 0; h < 4; h++){
      float acc = 0.f;
      #pragma unroll
      for (int cc = 0; cc < 16; cc++) acc += (xs[cc]-mean)*wzg_s[h*16+cc];
      upb[(h*32 + qq)*132 + kk] = (f16)(acc*rs);
    }
  }
  __syncthreads();

  const int l = tid & 63, w = tid >> 6;
  const int c = l & 15, q4 = l >> 4;
  const int h = w >> 1, qh = w & 1, m0 = qh*16;
  const f16x8 aq = ld8(Q + ((size_t)b*16384 + (size_t)nb*32 + m0 + c)*128 + h*32 + q4*8);
  const long kbase = (long)b*16384 + (long)nb*32 - 48;
  f32x4 sc[8];
  #pragma unroll
  for (int nt = 0; nt < 8; nt++){
    const f16x8 bf = ld8(K + (kbase + nt*16 + c)*128 + h*32 + q4*8);
    f32x4 zz = {0.f,0.f,0.f,0.f};
    sc[nt] = MFMA16(aq, bf, zz);
  }
  #pragma unroll
  for (int nt = 0; nt < 8; nt++){
    const int key = nt*16 + c;
    const long kt = (long)nb*32 - 48 + key;
    const bool inv = (kt < 0) || (kt >= 16384);
    #pragma unroll
    for (int r = 0; r < 4; r++){
      const float v = sc[nt][r] + (float)upb[(h*32 + m0 + q4*4 + r)*132 + key];
      sc[nt][r] = inv ? -1e9f : v;
    }
  }
  #pragma unroll
  for (int r = 0; r < 4; r++){
    float mx = sc[0][r];
    #pragma unroll
    for (int nt = 1; nt < 8; nt++) mx = fmaxf(mx, sc[nt][r]);
    #pragma unroll
    for (int o = 8; o; o >>= 1) mx = fmaxf(mx, __shfl_xor(mx, o));
    float sum = 0.f;
    #pragma unroll
    for (int nt = 0; nt < 8; nt++){ const float e = __expf(sc[nt][r]-mx); sc[nt][r] = e; sum += e; }
    #pragma unroll
    for (int o = 8; o; o >>= 1) sum += __shfl_xor(sum, o);
    const float inv = 1.f/sum;
    #pragma unroll
    for (int nt = 0; nt < 8; nt++) sc[nt][r] *= inv;
  }
  __syncthreads();
  #pragma unroll
  for (int nt = 0; nt < 8; nt++)
    #pragma unroll
    for (int r = 0; r < 4; r++)
      upb[(w*16 + q4*4 + r)*136 + nt*16 + c] = (f16)sc[nt][r];
  const f16* vb = VT + ((long)b*128)*16384 + (long)nb*32 - 48;
  f32x4 o0 = {0.f,0.f,0.f,0.f}, o1 = {0.f,0.f,0.f,0.f};
  #pragma unroll
  for (int kc = 0; kc < 4; kc++){
    const f16x8 pa = *(const f16x8*)&upb[(w*16 + c)*136 + kc*32 + q4*8];
    const f16x8 v0 = ld8(vb + (long)(h*32 + c)*16384 + kc*32 + q4*8);
    const f16x8 v1 = ld8(vb + (long)(h*32 + 16 + c)*16384 + kc*32 + q4*8);
    o0 = MFMA16(pa, v0, o0);
    o1 = MFMA16(pa, v1, o1);
  }
  #pragma unroll
  for (int r = 0; r < 4; r++){
    const size_t tok = (size_t)b*16384 + (size_t)nb*32 + m0 + q4*4 + r;
    Og[tok*128 + h*32 + c]      = (f16)o0[r];
    Og[tok*128 + h*32 + 16 + c] = (f16)o1[r];
  }
}

// ---------------------------------------------------------------------------
// Final: out = gl*((g.o)@Wo) + gs*(t@Wb). 64 rows/block; A-frags loaded once,
// all 8 col-tiles looped in-block (B stays L1/L2-hot) -> G/O/T read ONCE.
// ---------------------------------------------------------------------------
__global__ __launch_bounds__(256) void k_final(const f16* __restrict__ G, const f16* __restrict__ O,
    const f16* __restrict__ T, const f16* __restrict__ Wot, const f16* __restrict__ Wbt,
    const f16* __restrict__ GL, const f16* __restrict__ GS, float* __restrict__ out)
{
  const int l = threadIdx.x & 63, w = threadIdx.x >> 6;
  const int c = l & 15, q4 = l >> 4;
  const int mbase = blockIdx.x*64 + w*16;
  f16x8 ag[4], at[8];
  const f16* gp = G + (size_t)(mbase + c)*128 + q4*8;
  const f16* op = O + (size_t)(mbase + c)*128 + q4*8;
  #pragma unroll
  for (int kc = 0; kc < 4; kc++) ag[kc] = ld8(gp + kc*32) * ld8(op + kc*32);
  const f16* tp = T + (size_t)(mbase + c)*256 + q4*8;
  #pragma unroll
  for (int kc = 0; kc < 8; kc++) at[kc] = ld8(tp + kc*32);
  for (int nt = 0; nt < 8; nt++){
    const int cb = nt*16;
    f32x4 d1 = {0,0,0,0}, d2 = {0,0,0,0};
    #pragma unroll
    for (int kc = 0; kc < 4; kc++)
      d1 = MFMA16(ag[kc], ld8(Wot + (size_t)(cb + c)*128 + kc*32 + q4*8), d1);
    #pragma unroll
    for (int kc = 0; kc < 8; kc++)
      d2 = MFMA16(at[kc], ld8(Wbt + (size_t)(cb + c)*256 + kc*32 + q4*8), d2);
    #pragma unroll
    for (int r = 0; r < 4; r++){
      const size_t row = mbase + q4*4 + r;
      const float glv = (float)GL[row*128 + cb + c];
      const float gsv = (float)GS[row*128 + cb + c];
      out[row*128 + cb + c] = glv*d1[r] + gsv*d2[r];
    }
  }
}

// ---------------------------------------------------------------------------
extern "C" void kernel_launch(void* const* d_in, const int* in_sizes, int n_in,
                              void* d_out, int out_size, void* d_ws, size_t ws_size,
                              hipStream_t stream)
{
  (void)in_sizes; (void)n_in; (void)out_size; (void)ws_size;
  const float* a        = (const float*)d_in[0];
  const float* s        = (const float*)d_in[1];
  const float* z        = (const float*)d_in[2];
  const float* apb_gamma= (const float*)d_in[3];
  const float* apb_Wg   = (const float*)d_in[4];
  const float* apb_bg   = (const float*)d_in[5];
  const float* apb_Wskip= (const float*)d_in[6];
  const float* Wq       = (const float*)d_in[7];
  const float* bq       = (const float*)d_in[8];
  const float* Wk       = (const float*)d_in[9];
  const float* Wv       = (const float*)d_in[10];
  const float* Wgate    = (const float*)d_in[11];
  const float* Wo       = (const float*)d_in[12];
  const float* gamma_z  = (const float*)d_in[13];
  const float* Wz       = (const float*)d_in[14];
  const float* Wsl      = (const float*)d_in[15];
  const float* bsl      = (const float*)d_in[16];
  const float* ct_gamma = (const float*)d_in[17];
  const float* ct_Wg    = (const float*)d_in[18];
  const float* ct_bg    = (const float*)d_in[19];
  const float* ct_Wskip = (const float*)d_in[20];
  const float* Wa1      = (const float*)d_in[21];
  const float* Wa2      = (const float*)d_in[22];
  const float* Wb       = (const float*)d_in[23];
  const float* Wss      = (const float*)d_in[24];
  const float* bss      = (const float*)d_in[25];

  f16* W0 = (f16*)d_ws;
  const size_t SL = (size_t)32768*128;
  f16* qv = W0 + 0*SL;
  f16* kv = W0 + 1*SL;
  f16* vt = W0 + 2*SL;
  f16* gv = W0 + 3*SL;
  f16* tv = W0 + 4*SL;   // 2 slots (32768 x 256)
  f16* gl = W0 + 6*SL;
  f16* gs = W0 + 7*SL;
  f16* ov = W0 + 8*SL;
  f16* wA  = W0 + 9*SL;
  f16* wC  = wA  + 256*128;
  f16* wQK = wC  + 256*128;
  f16* wVG = wQK + 256*128;
  f16* wSG = wVG + 256*128;
  f16* wAB = wSG + 256*128;
  f16* wO  = wAB + 512*128;
  f16* wBt = wO  + 128*128;
  float* wzg = (float*)(wBt + 128*256);
  float* Slv = wzg + 64;
  float* Ssv = Slv + 128;

  k_prep<<<dim3(64),256,0,stream>>>(apb_gamma,apb_Wg,apb_Wskip, ct_gamma,ct_Wg,ct_Wskip,
      Wq,Wk,Wv,Wgate, Wsl,Wss, Wa1,Wa2, Wo,Wb, gamma_z,Wz,
      wA,wC,wQK,wVG,wSG,wAB,wO,wBt,wzg,Slv,Ssv);
  k_pre<<<dim3(512),256,0,stream>>>(a,s, wA,wC,wQK,wVG,wSG,wAB,
      apb_bg,ct_bg,bq,bsl,bss,Slv,Ssv, qv,kv,vt,gv,tv,gl,gs);
  k_attn<<<dim3(1024),512,0,stream>>>(qv,kv,vt,z,wzg,ov);
  k_final<<<dim3(512),256,0,stream>>>(gv,ov,tv,wO,wBt,gl,gs,(float*)d_out);
}